// Round 4
// baseline (5632.066 us; speedup 1.0000x reference)
//
#include <hip/hip_runtime.h>
#include <hip/hip_bf16.h>
#include <stdint.h>
#include <stddef.h>

using bf16 = __hip_bfloat16;
typedef short s16x8 __attribute__((ext_vector_type(8)));   // 8 bf16 = one MFMA frag (4 VGPRs)
typedef float f32x4 __attribute__((ext_vector_type(4)));

#define MFMA16(a, b, c) __builtin_amdgcn_mfma_f32_16x16x32_bf16((a), (b), (c), 0, 0, 0)

typedef __attribute__((address_space(1))) void gvoid;
typedef __attribute__((address_space(3))) void lvoid;
// global -> LDS direct copy, 16B per lane; LDS dest = wave-uniform base + lane*16
#define GLL16(gp, lp) __builtin_amdgcn_global_load_lds((gvoid*)(void*)(gp), (lvoid*)(lp), 16, 0, 0)

__device__ __forceinline__ short f2bf(float x) {
    bf16 h = __float2bfloat16(x);
    return __builtin_bit_cast(short, h);
}

// f32 -> bf16 elementwise, n % 1024 == 0
__global__ void cvt_bf16(const float* __restrict__ in, bf16* __restrict__ out, int n) {
    int i = (blockIdx.x * blockDim.x + threadIdx.x) * 4;
    if (i < n) {
        float4 v = *(const float4*)(in + i);
        out[i + 0] = __float2bfloat16(v.x);
        out[i + 1] = __float2bfloat16(v.y);
        out[i + 2] = __float2bfloat16(v.z);
        out[i + 3] = __float2bfloat16(v.w);
    }
}

// ---------------------------------------------------------------------------
// C[om(m)][n] = bias[n] + sum_k A[m][k] * Bt[n][k]     (K = N = 1024)
// A_F32: A is f32, staged via register convert + ds_write_b128 (XOR-swizzled
//        chunk layout identical to the GLL16 path). Else A is bf16 via GLL16.
// OUT_F32: store f32 else bf16.  bias always f32.
// REMAP: 0 none; 1 m=b*512+t -> t*64+b ; 2 m=t*64+b -> b*512+t
// 128x128 tile, BK=64, 4 waves each 64x64 (m97-verified structure).
// ---------------------------------------------------------------------------
template<bool A_F32, bool OUT_F32, int REMAP>
__global__ __launch_bounds__(256) void gemm_bt(
    const void* __restrict__ Ap, const bf16* __restrict__ Bt,
    const float* __restrict__ bias, void* __restrict__ Cp)
{
    __shared__ __align__(16) bf16 lA[128 * 64];
    __shared__ __align__(16) bf16 lB[128 * 64];

    const int tid  = threadIdx.x;
    const int lane = tid & 63, wv = tid >> 6;
    const int wm = wv & 1, wn = wv >> 1;
    const int quad = lane >> 4, l16 = lane & 15;
    const int m0 = blockIdx.x * 128, n0 = blockIdx.y * 128;

    const int sr = lane >> 3;
    const int sc = ((lane & 7) ^ sr) * 8;   // element offset of swizzled 16B chunk

    const int ar = tid >> 1;                // f32-A staging: row, half
    const int ah = tid & 1;

    f32x4 acc[4][4] = {};

    for (int ko = 0; ko < 1024; ko += 64) {
        if constexpr (A_F32) {
            const float* Af = (const float*)Ap;
#pragma unroll
            for (int i = 0; i < 4; ++i) {
                const int c = ah * 4 + i;                    // source chunk 0..7
                const float* src = Af + (size_t)(m0 + ar) * 1024 + ko + c * 8;
                float4 v0 = *(const float4*)(src);
                float4 v1 = *(const float4*)(src + 4);
                s16x8 w;
                w[0] = f2bf(v0.x); w[1] = f2bf(v0.y); w[2] = f2bf(v0.z); w[3] = f2bf(v0.w);
                w[4] = f2bf(v1.x); w[5] = f2bf(v1.y); w[6] = f2bf(v1.z); w[7] = f2bf(v1.w);
                *(s16x8*)((char*)lA + ar * 128 + ((c ^ (ar & 7)) << 4)) = w;
            }
#pragma unroll
            for (int qi = 0; qi < 4; ++qi) {
                const int q = wv * 4 + qi;
                GLL16(Bt + (size_t)(n0 + q * 8 + sr) * 1024 + ko + sc, (char*)lB + q * 1024);
            }
        } else {
            const bf16* Ab = (const bf16*)Ap;
#pragma unroll
            for (int qi = 0; qi < 4; ++qi) {
                const int q = wv * 4 + qi;
                GLL16(Ab + (size_t)(m0 + q * 8 + sr) * 1024 + ko + sc, (char*)lA + q * 1024);
                GLL16(Bt + (size_t)(n0 + q * 8 + sr) * 1024 + ko + sc, (char*)lB + q * 1024);
            }
        }
        __syncthreads();
#pragma unroll
        for (int kc = 0; kc < 2; ++kc) {
            s16x8 af[4], bg[4];
#pragma unroll
            for (int mt = 0; mt < 4; ++mt) {
                const int r = 64 * wm + 16 * mt + l16;
                const int c = kc * 4 + quad;
                af[mt] = *(const s16x8*)((const char*)lA + r * 128 + ((c ^ (r & 7)) * 16));
            }
#pragma unroll
            for (int nt = 0; nt < 4; ++nt) {
                const int r = 64 * wn + 16 * nt + l16;
                const int c = kc * 4 + quad;
                bg[nt] = *(const s16x8*)((const char*)lB + r * 128 + ((c ^ (r & 7)) * 16));
            }
#pragma unroll
            for (int mt = 0; mt < 4; ++mt)
#pragma unroll
                for (int nt = 0; nt < 4; ++nt)
                    acc[mt][nt] = MFMA16(af[mt], bg[nt], acc[mt][nt]);
        }
        __syncthreads();
    }

    float bv[4];
#pragma unroll
    for (int nt = 0; nt < 4; ++nt)
        bv[nt] = bias[n0 + 64 * wn + 16 * nt + l16];

    // D layout: row = quad*4 + reg, col = lane&15  (m89/m91-verified)
#pragma unroll
    for (int mt = 0; mt < 4; ++mt) {
#pragma unroll
        for (int r = 0; r < 4; ++r) {
            const int m = m0 + 64 * wm + 16 * mt + 4 * quad + r;
            int om = m;
            if constexpr (REMAP == 1)      om = ((m & 511) << 6) | (m >> 9); // b*512+t -> t*64+b
            else if constexpr (REMAP == 2) om = ((m & 63) << 9) | (m >> 6);  // t*64+b -> b*512+t
#pragma unroll
            for (int nt = 0; nt < 4; ++nt) {
                const int n = n0 + 64 * wn + 16 * nt + l16;
                const float val = acc[mt][nt][r] + bv[nt];
                if constexpr (OUT_F32) ((float*)Cp)[(size_t)om * 1024 + n] = val;
                else ((bf16*)Cp)[(size_t)om * 1024 + n] = __float2bfloat16(val);
            }
        }
    }
}

// ---------------------------------------------------------------------------
// Persistent scan: for t=1..511:  A[t] = U[t] + A[t-1] @ Waa^T  (in UA, bf16)
// UA: [T=512][B=64][1024].  A[0] = U[0] from phase A (kernel boundary).
// 256 WGs x 1 wave.  WG(bi=wg&3, nj=wg>>2): batch rows 16bi..+15, act cols
// 16nj..+15.  Waa slice (16 rows x 1024, 32 KB) resident in LDS.
// Sync: flag slot per WG (flags[bi*64+nj] = last completed step; release-fence
// + agent-scope store).  Step t (t>=2) spins until all 64 flags of group bi
// >= t-1, then acquire-fence.  No RMW contention; 4 independent groups.
// No WAR hazards: UA slot t is written only by its own-slice owner, and the
// release fence drains lgkmcnt so LDS reuse across steps is ordered.
// ---------------------------------------------------------------------------
__global__ __launch_bounds__(64, 1) void rnn_scan(
    const bf16* __restrict__ Waa, bf16* __restrict__ UA,
    unsigned* __restrict__ flags)
{
    __shared__ __align__(16) bf16 lW[16 * 1024];   // 32 KB
    __shared__ __align__(16) bf16 lA[16 * 1024];   // 32 KB

    const int lane = threadIdx.x;
    const int wg = blockIdx.x;
    const int bi = wg & 3;              // batch-row slice (0..3)
    const int nj = wg >> 2;             // act-col slice  (0..63)
    const int quad = lane >> 4, l16 = lane & 15;
    const int swz = l16 & 7;

    // stage Waa rows [16nj, +16): inst q -> row r=q>>1, chunk-pos cp=(q&1)*64+lane,
    // source chunk c = cp^(r&7); LDS: row r pos cp at byte r*2048+cp*16.
#pragma unroll 8
    for (int q = 0; q < 32; ++q) {
        const int r  = q >> 1;
        const int cp = ((q & 1) << 6) | lane;
        const int c  = cp ^ (r & 7);
        GLL16(Waa + (size_t)(16 * nj + r) * 1024 + c * 8, (char*)lW + q * 1024);
    }

    unsigned* gflags = flags + bi * 64;

    for (int t = 1; t < 512; ++t) {
        if (t > 1) {
            const unsigned want = (unsigned)(t - 1);
            unsigned v = __hip_atomic_load(&gflags[lane], __ATOMIC_RELAXED,
                                           __HIP_MEMORY_SCOPE_AGENT);
            while (!__all(v >= want)) {
                __builtin_amdgcn_s_sleep(1);
                v = __hip_atomic_load(&gflags[lane], __ATOMIC_RELAXED,
                                      __HIP_MEMORY_SCOPE_AGENT);
            }
            __builtin_amdgcn_fence(__ATOMIC_ACQUIRE, "agent");
        }

        // stage A[t-1] rows [16bi, +16)
        const bf16* src = UA + ((size_t)(t - 1) * 64 + 16 * bi) * 1024;
#pragma unroll 8
        for (int q = 0; q < 32; ++q) {
            const int r  = q >> 1;
            const int cp = ((q & 1) << 6) | lane;
            const int c  = cp ^ (r & 7);
            GLL16(src + (size_t)r * 1024 + c * 8, (char*)lA + q * 1024);
        }

        // acc init from U[t] own slice (D layout: row = 4*quad+rr, col = l16)
        const bf16* urow = UA + ((size_t)(t * 64 + 16 * bi + 4 * quad)) * 1024
                              + 16 * nj + l16;
        f32x4 acc[4] = {};
#pragma unroll
        for (int rr = 0; rr < 4; ++rr)
            acc[0][rr] = __bfloat162float(urow[(size_t)rr * 1024]);

        __builtin_amdgcn_s_waitcnt(0);   // drain LDS-DMA before ds_read
        __syncthreads();

        // 4 independent 8-deep MFMA chains (latency hiding), summed at the end
#pragma unroll
        for (int ch = 0; ch < 4; ++ch)
#pragma unroll
            for (int j = 0; j < 8; ++j) {
                const int c = (ch * 8 + j) * 4 + quad;       // chunk 0..127
                const int p = (c ^ swz) << 4;
                s16x8 av = *(const s16x8*)((const char*)lA + l16 * 2048 + p);
                s16x8 wf = *(const s16x8*)((const char*)lW + l16 * 2048 + p);
                acc[ch] = MFMA16(av, wf, acc[ch]);
            }
        f32x4 r2 = (acc[0] + acc[1]) + (acc[2] + acc[3]);

        // write A[t] own slice (overwrites the U[t] slice just consumed)
        bf16* drow = UA + ((size_t)(t * 64 + 16 * bi + 4 * quad)) * 1024
                        + 16 * nj + l16;
#pragma unroll
        for (int rr = 0; rr < 4; ++rr)
            drow[(size_t)rr * 1024] = __float2bfloat16(r2[rr]);

        __builtin_amdgcn_fence(__ATOMIC_RELEASE, "agent");   // drain + make visible
        if (lane == 0)
            __hip_atomic_store(&gflags[nj], (unsigned)t, __ATOMIC_RELAXED,
                               __HIP_MEMORY_SCOPE_AGENT);
    }
}

// ---------------------------------------------------------------------------
extern "C" void kernel_launch(void* const* d_in, const int* in_sizes, int n_in,
                              void* d_out, int out_size, void* d_ws, size_t ws_size,
                              hipStream_t stream) {
    const float* X   = (const float*)d_in[0];   // [64,512,1024] f32
    const float* Wax = (const float*)d_in[1];   // [1024,1024]   f32
    const float* Waa = (const float*)d_in[2];   // [1024,1024]   f32
    const float* ba  = (const float*)d_in[3];   // [1024]        f32
    const float* Wy  = (const float*)d_in[4];   // [1024,1024]   f32
    const float* by  = (const float*)d_in[5];   // [1024]        f32

    char* ws = (char*)d_ws;
    bf16* UA   = (bf16*)ws;                                   // 64 MB: [512][64][1024]
    bf16* Waxb = (bf16*)(ws + 67108864);                      // 2 MB
    bf16* Waab = (bf16*)(ws + 67108864 + 2097152);            // 2 MB
    bf16* Wyb  = (bf16*)(ws + 67108864 + 2 * 2097152);        // 2 MB
    unsigned* flags = (unsigned*)(ws + 67108864 + 3 * 2097152); // 1 KB (4 groups x 64)

    hipMemsetAsync(flags, 0, 4 * 64 * sizeof(unsigned), stream);

    const int NW = 1024 * 1024;
    cvt_bf16<<<dim3(NW / 1024), dim3(256), 0, stream>>>(Wax, Waxb, NW);
    cvt_bf16<<<dim3(NW / 1024), dim3(256), 0, stream>>>(Waa, Waab, NW);
    cvt_bf16<<<dim3(NW / 1024), dim3(256), 0, stream>>>(Wy,  Wyb,  NW);

    dim3 grid(256, 8), blk(256);
    // Phase A: U = X @ Wax^T + ba   (f32 A-operand, rows b*512+t -> t*64+b, bf16 out)
    gemm_bt<true, false, 1><<<grid, blk, 0, stream>>>(X, Waxb, ba, UA);
    // Phase B: persistent sequential recurrence (1 dispatch, flag-synced)
    rnn_scan<<<dim3(256), dim3(64), 0, stream>>>(Waab, UA, flags);
    // Phase C: Y = A @ Wy^T + by    (rows t*64+b -> b*512+t, f32 out to d_out)
    gemm_bt<false, true, 2><<<grid, blk, 0, stream>>>(UA, Wyb, by, (float*)d_out);
}